// Round 3
// baseline (115.053 us; speedup 1.0000x reference)
//
#include <hip/hip_runtime.h>

// NCE loss: out0 = align + w*uniform, out1 = align, out2 = uniform
// align[n]   = logsig(ref[n]·pos[n]/T)
// uniform[n] = mean_m logsig(-ref[n]·neg[m]/T)
// N=M=8192, D=512, T=0.5, w=1.0

typedef __attribute__((ext_vector_type(8))) short short8;
typedef __attribute__((ext_vector_type(8))) unsigned short ushort8;
typedef __attribute__((ext_vector_type(4))) float f32x4;

constexpr int N_ = 8192;
constexpr int M_ = 8192;
constexpr int D_ = 512;
constexpr float INV_T = 2.0f;
constexpr float NEG_W = 1.0f;
constexpr float LOG2E = 1.4426950408889634f;
constexpr float LN2   = 0.6931471805599453f;

#define BM 256
#define BN 256
#define BK 32
#define NKT 16     // 512 / 32
#define DEPTH 4    // LDS ring depth (tiles in flight: compute + 3 staged)
// LDS: DEPTH * (256*32*2B) per matrix = 64 KiB * 2 = 128 KiB total

__device__ __forceinline__ unsigned short f2bf(float f) {
  unsigned int u = __builtin_bit_cast(unsigned int, f);
  u += 0x7FFFu + ((u >> 16) & 1u);  // RNE
  return (unsigned short)(u >> 16);
}

__device__ __forceinline__ float logsig_neg(float s) {
  // log sigmoid(-s) = min(-s,0) - log1p(exp(-|s|))
  float t = __builtin_fabsf(s);
  float e = __builtin_amdgcn_exp2f(-t * LOG2E);
  float l = __builtin_amdgcn_logf(1.0f + e) * LN2;
  return fminf(-s, 0.0f) - l;
}

// fp32 -> bf16 with the BK=32 involution swizzle pre-applied per row:
// within each 64B K-tile segment, 16B chunk w is stored at position
// w ^ s(row), s(row) = (row&3)^((row>>2)&3). Linear global_load_lds
// staging then yields a bank-conflict-free swizzled LDS tile.
__global__ __launch_bounds__(256) void cvt_pack(
    const float* __restrict__ refp, const float* __restrict__ negp,
    unsigned short* __restrict__ abf, unsigned short* __restrict__ bbf) {
  const int b = blockIdx.x;
  const float* src = (b < 2048) ? refp : negp;
  unsigned short* dst = (b < 2048) ? abf : bbf;
  const int i = (b & 2047) * 256 + threadIdx.x;  // 16B-chunk index
  const f32x4* s = reinterpret_cast<const f32x4*>(src) + (size_t)i * 2;
  f32x4 v0 = s[0], v1 = s[1];
  ushort8 o;
#pragma unroll
  for (int j = 0; j < 4; ++j) {
    o[j]     = f2bf(v0[j]);
    o[4 + j] = f2bf(v1[j]);
  }
  const unsigned int row = (unsigned int)i >> 6;  // 64 chunks per 512-el row
  const unsigned int c   = (unsigned int)i & 63;
  const unsigned int seg = c >> 2;   // K-tile (64B)
  const unsigned int w   = c & 3;    // chunk within tile
  const unsigned int sw  = (row & 3u) ^ ((row >> 2) & 3u);
  const size_t byte = (size_t)row * 1024 + seg * 64 + (size_t)((w ^ sw) << 4);
  *reinterpret_cast<ushort8*>(reinterpret_cast<char*>(dst) + byte) = o;
}

__global__ __launch_bounds__(512, 2) void nce_gemm(
    const unsigned short* __restrict__ A,  // ref bf16 (pre-swizzled)
    const unsigned short* __restrict__ B,  // neg bf16 (pre-swizzled)
    float* __restrict__ rowsum) {          // (N,) fp32, pre-zeroed
  extern __shared__ char lds[];
  char* AsB = lds;                   // DEPTH x 16 KiB
  char* BsB = lds + DEPTH * 16384;   // DEPTH x 16 KiB

  const int tid  = threadIdx.x;
  const int lane = tid & 63;
  const int wid  = tid >> 6;   // 0..7
  const int wr   = wid >> 2;   // 0..1  (A-half)
  const int wc   = wid & 3;    // 0..3  (B quarter: 64 cols)

  // XCD band swizzle: 1024 blocks, 8 XCDs, 4 row-bands per XCD,
  // column-major within band (B-tile reuse in per-XCD L2).
  const int bid  = blockIdx.x;
  const int x    = bid & 7;
  const int t    = bid >> 3;  // 0..127
  const int brow = (x * 4 + (t & 3)) * BM;
  const int bcol = (t >> 2) * BN;

  // per-lane staging source address (pre-swizzled global layout):
  // lane l covers row (l>>2), chunk (l&3); stored chunk position
  // (l&3) ^ s(row), s = ((l>>2)&3) ^ ((l>>4)&3)
  const unsigned int pl =
      ((unsigned int)lane & 3u) ^ (((unsigned int)lane >> 2) & 3u) ^
      (((unsigned int)lane >> 4) & 3u);
  const char* gA = reinterpret_cast<const char*>(A) +
                   (size_t)(brow + wid * 16 + (lane >> 2)) * 1024 + pl * 16;
  const char* gB = reinterpret_cast<const char*>(B) +
                   (size_t)(bcol + wid * 16 + (lane >> 2)) * 1024 + pl * 16;

  f32x4 acc[8][4] = {};

#define STAGE(kt)                                                             \
  {                                                                           \
    const int b_ = (kt) & (DEPTH - 1);                                        \
    _Pragma("unroll") for (int j = 0; j < 2; ++j) {                           \
      __builtin_amdgcn_global_load_lds(                                       \
          (const __attribute__((address_space(1))) unsigned int*)(            \
              gA + (size_t)j * 131072 + (size_t)(kt) * 64),                   \
          (__attribute__((address_space(3))) unsigned int*)(                  \
              AsB + b_ * 16384 + (j * 128 + wid * 16) * 64),                  \
          16, 0, 0);                                                          \
      __builtin_amdgcn_global_load_lds(                                       \
          (const __attribute__((address_space(1))) unsigned int*)(            \
              gB + (size_t)j * 131072 + (size_t)(kt) * 64),                   \
          (__attribute__((address_space(3))) unsigned int*)(                  \
              BsB + b_ * 16384 + (j * 128 + wid * 16) * 64),                  \
          16, 0, 0);                                                          \
    }                                                                         \
  }

  // fragment-read constants
  const int r    = lane & 15;
  const int g    = lane >> 4;  // k-chunk group (kk = g*8)
  const int cs16 = ((g ^ (r & 3) ^ ((r >> 2) & 3)) << 4);
  const int rbA  = (wr * 128 + r) * 64 + cs16;
  const int rbB  = (wc * 64 + r) * 64 + cs16;

  // prologue: stage tiles 0,1,2 (12 loads); wait tile 0 (<=8 outstanding)
  STAGE(0);
  STAGE(1);
  STAGE(2);
  asm volatile("s_waitcnt vmcnt(8)" ::: "memory");
  __builtin_amdgcn_s_barrier();
  asm volatile("" ::: "memory");

#pragma unroll
  for (int kt = 0; kt < NKT; ++kt) {
    const char* Ab = AsB + (kt & (DEPTH - 1)) * 16384;
    const char* Bb = BsB + (kt & (DEPTH - 1)) * 16384;

    if (kt + 3 < NKT) STAGE(kt + 3);  // issue prefetch first

    short8 bfrag[4], af[4];
#pragma unroll
    for (int nf = 0; nf < 4; ++nf)
      bfrag[nf] = *reinterpret_cast<const short8*>(Bb + rbB + nf * 1024);
#pragma unroll
    for (int mf = 0; mf < 4; ++mf)
      af[mf] = *reinterpret_cast<const short8*>(Ab + rbA + mf * 1024);

    __builtin_amdgcn_s_setprio(1);
#pragma unroll
    for (int mf = 0; mf < 4; ++mf)
#pragma unroll
      for (int nf = 0; nf < 4; ++nf)
        acc[mf][nf] = __builtin_amdgcn_mfma_f32_16x16x32_bf16(
            af[mf], bfrag[nf], acc[mf][nf], 0, 0, 0);
    __builtin_amdgcn_s_setprio(0);

    short8 ah[4];
#pragma unroll
    for (int mf = 0; mf < 4; ++mf)
      ah[mf] = *reinterpret_cast<const short8*>(Ab + rbA + 4096 + mf * 1024);

    __builtin_amdgcn_s_setprio(1);
#pragma unroll
    for (int mf = 0; mf < 4; ++mf)
#pragma unroll
      for (int nf = 0; nf < 4; ++nf)
        acc[4 + mf][nf] = __builtin_amdgcn_mfma_f32_16x16x32_bf16(
            ah[mf], bfrag[nf], acc[4 + mf][nf], 0, 0, 0);
    __builtin_amdgcn_s_setprio(0);

    // tile boundary: counted drain (tile kt+1 complete; 2 tiles in flight)
    if (kt < NKT - 1) {
      if (kt < NKT - 3)
        asm volatile("s_waitcnt vmcnt(8)" ::: "memory");
      else if (kt == NKT - 3)
        asm volatile("s_waitcnt vmcnt(4)" ::: "memory");
      else
        asm volatile("s_waitcnt vmcnt(0)" ::: "memory");
      __builtin_amdgcn_s_barrier();
      asm volatile("" ::: "memory");
    }
  }
#undef STAGE

  // epilogue: logsig(-s*INV_T), reduce over this tile's 64 cols per wave,
  // then atomic per row (fp32, device scope).
  float part[32];
#pragma unroll
  for (int mf = 0; mf < 8; ++mf)
#pragma unroll
    for (int rr = 0; rr < 4; ++rr) {
      float ssum = 0.0f;
#pragma unroll
      for (int nf = 0; nf < 4; ++nf) {
        float s = acc[mf][nf][rr] * INV_T;
        ssum += logsig_neg(s);
      }
      part[mf * 4 + rr] = ssum;
    }
#pragma unroll
  for (int i = 0; i < 32; ++i) {
    float v = part[i];
    v += __shfl_xor(v, 1);
    v += __shfl_xor(v, 2);
    v += __shfl_xor(v, 4);
    v += __shfl_xor(v, 8);
    part[i] = v;
  }
  if ((lane & 15) == 0) {
    const int gq = lane >> 4;  // row quad within fragment
#pragma unroll
    for (int mf = 0; mf < 8; ++mf)
#pragma unroll
      for (int rr = 0; rr < 4; ++rr)
        atomicAdd(&rowsum[brow + wr * 128 + mf * 16 + gq * 4 + rr],
                  part[mf * 4 + rr]);
  }
}

__global__ __launch_bounds__(256) void nce_combine(
    const float* __restrict__ ref, const float* __restrict__ pos,
    const float* __restrict__ rowsum, float* __restrict__ out) {
  const int wid  = threadIdx.x >> 6;
  const int lane = threadIdx.x & 63;
  const int n    = blockIdx.x * 4 + wid;

  const f32x4* pr =
      reinterpret_cast<const f32x4*>(ref + (size_t)n * D_ + lane * 8);
  const f32x4* pp =
      reinterpret_cast<const f32x4*>(pos + (size_t)n * D_ + lane * 8);
  f32x4 a0 = pr[0], a1 = pr[1], b0 = pp[0], b1 = pp[1];
  float d = 0.0f;
#pragma unroll
  for (int i = 0; i < 4; ++i) d = __builtin_fmaf(a0[i], b0[i], d);
#pragma unroll
  for (int i = 0; i < 4; ++i) d = __builtin_fmaf(a1[i], b1[i], d);
#pragma unroll
  for (int s = 1; s < 64; s <<= 1) d += __shfl_xor(d, s);

  if (lane == 0) {
    float z = d * INV_T;
    float align   = logsig_neg(-z);
    float uniform = rowsum[n] * (1.0f / (float)M_);
    out[n]          = align + NEG_W * uniform;
    out[N_ + n]     = align;
    out[2 * N_ + n] = uniform;
  }
}

extern "C" void kernel_launch(void* const* d_in, const int* in_sizes, int n_in,
                              void* d_out, int out_size, void* d_ws,
                              size_t ws_size, hipStream_t stream) {
  const float* ref = (const float*)d_in[0];
  const float* pos = (const float*)d_in[1];
  const float* neg = (const float*)d_in[2];
  float* out = (float*)d_out;

  float* rowsum = (float*)d_ws;                                  // 32 KB
  unsigned short* abf = (unsigned short*)((char*)d_ws + 32768);  // 8 MB
  unsigned short* bbf = abf + (size_t)N_ * D_;                   // 8 MB

  // allow 128 KiB dynamic LDS (above the 64 KiB default)
  (void)hipFuncSetAttribute((const void*)nce_gemm,
                            hipFuncAttributeMaxDynamicSharedMemorySize,
                            131072);

  hipMemsetAsync(rowsum, 0, N_ * sizeof(float), stream);
  cvt_pack<<<4096, 256, 0, stream>>>(ref, neg, abf, bbf);
  nce_gemm<<<1024, 512, 131072, stream>>>(abf, bbf, rowsum);
  nce_combine<<<N_ / 4, 256, 0, stream>>>(ref, pos, rowsum, out);
}

// Round 4
// 109.246 us; speedup vs baseline: 1.0532x; 1.0532x over previous
//
#include <hip/hip_runtime.h>

// NCE loss: out0 = align + w*uniform, out1 = align, out2 = uniform
// align[n]   = logsig(ref[n]·pos[n]/T)
// uniform[n] = mean_m logsig(-ref[n]·neg[m]/T)
// N=M=8192, D=512, T=0.5, w=1.0
//
// nce_gemm: 256x256 tile, BK=64, 8 waves (2x4), 8-phase interleave
// (T2 swizzle + T3/T4 counted vmcnt + T5 setprio), per m201 template.

typedef __attribute__((ext_vector_type(8))) short short8;
typedef __attribute__((ext_vector_type(8))) unsigned short ushort8;
typedef __attribute__((ext_vector_type(4))) float f32x4;

constexpr int N_ = 8192;
constexpr int M_ = 8192;
constexpr int D_ = 512;
constexpr float INV_T = 2.0f;
constexpr float NEG_W = 1.0f;
constexpr float LOG2E = 1.4426950408889634f;
constexpr float LN2   = 0.6931471805599453f;

__device__ __forceinline__ unsigned short f2bf(float f) {
  unsigned int u = __builtin_bit_cast(unsigned int, f);
  u += 0x7FFFu + ((u >> 16) & 1u);  // RNE
  return (unsigned short)(u >> 16);
}

__device__ __forceinline__ float logsig_neg(float s) {
  // log sigmoid(-s) = min(-s,0) - log1p(exp(-|s|))
  float t = __builtin_fabsf(s);
  float e = __builtin_amdgcn_exp2f(-t * LOG2E);
  float l = __builtin_amdgcn_logf(1.0f + e) * LN2;
  return fminf(-s, 0.0f) - l;
}

// fp32 -> bf16 with the intra-row 16B-chunk XOR involution pre-applied
// (chunk c of row stored at c ^ (row&7) within each 128B K-segment), so
// linear global_load_lds staging yields the swizzled LDS layout.
// (Identical to the round-2 version: measured 0 bank conflicts.)
__global__ __launch_bounds__(256) void cvt_pack(
    const float* __restrict__ refp, const float* __restrict__ negp,
    unsigned short* __restrict__ abf, unsigned short* __restrict__ bbf) {
  const int b = blockIdx.x;
  const float* src = (b < 2048) ? refp : negp;
  unsigned short* dst = (b < 2048) ? abf : bbf;
  const int i = (b & 2047) * 256 + threadIdx.x;  // 16B-chunk index
  const f32x4* s = reinterpret_cast<const f32x4*>(src) + (size_t)i * 2;
  f32x4 v0 = s[0], v1 = s[1];
  ushort8 o;
#pragma unroll
  for (int j = 0; j < 4; ++j) {
    o[j]     = f2bf(v0[j]);
    o[4 + j] = f2bf(v1[j]);
  }
  const unsigned int row = (unsigned int)i >> 6;  // 64 chunks per 512-el row
  const unsigned int seg = ((unsigned int)i >> 3) & 7;  // 128B K-segment
  const unsigned int c   = (unsigned int)i & 7;         // chunk in segment
  const size_t byte =
      (size_t)row * 1024 + seg * 128 + (size_t)((c ^ (row & 7u)) << 4);
  *reinterpret_cast<ushort8*>(reinterpret_cast<char*>(dst) + byte) = o;
}

#define VMCNT(n) asm volatile("s_waitcnt vmcnt(" #n ")" ::: "memory")
#define BAR()                              \
  {                                        \
    asm volatile("" ::: "memory");         \
    __builtin_amdgcn_s_barrier();          \
    asm volatile("" ::: "memory");         \
  }

__global__ __launch_bounds__(512, 2) void nce_gemm(
    const unsigned short* __restrict__ A,  // ref bf16, pre-swizzled rows
    const unsigned short* __restrict__ B,  // neg bf16, pre-swizzled rows
    float* __restrict__ rowsum) {          // (N,) fp32, pre-zeroed
  extern __shared__ char lds[];
  char* As = lds;           // 2 bufs x 256 rows x 128 B
  char* Bs = lds + 65536;   // 2 bufs x 256 rows x 128 B

  const int tid  = threadIdx.x;
  const int lane = tid & 63;
  const int wid  = tid >> 6;   // 0..7
  const int wr   = wid >> 2;   // 0..1 (A half: 128 rows)
  const int wc   = wid & 3;    // 0..3 (B quarter: 64 cols)

  // XCD band swizzle: 1024 blocks, 8 XCDs, 4 row-bands/XCD, col-major in band
  const int bid  = blockIdx.x;
  const int x    = bid & 7;
  const int t    = bid >> 3;  // 0..127
  const int brow = (x * 4 + (t & 3)) * 256;
  const int bcol = (t >> 2) * 256;

  // staging lane constants (global stored layout == desired LDS layout,
  // both keyed on row&7, so NO xor on the source side)
  const int lr = lane >> 3;  // row within 8-row group
  const size_t laneoff = (size_t)lr * 1024 + (size_t)(lane & 7) * 16;
  const char* gA = reinterpret_cast<const char*>(A) + (size_t)brow * 1024 + laneoff;
  const char* gB = reinterpret_cast<const char*>(B) + (size_t)bcol * 1024 + laneoff;

  // fragment-read constants
  const int r  = lane & 15;
  const int g4 = lane >> 4;                 // k-chunk group
  const int c0 = ((g4 ^ (r & 7)) << 4);     // k=0 stored-chunk byte
  const int c1 = (((4 + g4) ^ (r & 7)) << 4);

  f32x4 acc[8][4] = {};
  short8 a[4][2], b0[2][2], b1[2][2];

  // ---- staging: one half-tile (16 KiB) = 2 glds per thread ----
#define STAGE_A(T, uh)                                                        \
  {                                                                           \
    _Pragma("unroll") for (int j = 0; j < 2; ++j) {                           \
      const int u  = wid * 2 + j;                                             \
      const int rb = (u >> 3) * 128 + (u & 7) * 8 + (uh) * 64;                \
      __builtin_amdgcn_global_load_lds(                                       \
          (const __attribute__((address_space(1))) unsigned int*)(            \
              gA + (size_t)rb * 1024 + (size_t)(T) * 128),                    \
          (__attribute__((address_space(3))) unsigned int*)(                  \
              As + ((T) & 1) * 32768 + rb * 128),                             \
          16, 0, 0);                                                          \
    }                                                                         \
  }
#define STAGE_B(T, uh)                                                        \
  {                                                                           \
    _Pragma("unroll") for (int j = 0; j < 2; ++j) {                           \
      const int u  = wid * 2 + j;                                             \
      const int rb = (u >> 2) * 64 + (u & 3) * 8 + (uh) * 32;                 \
      __builtin_amdgcn_global_load_lds(                                       \
          (const __attribute__((address_space(1))) unsigned int*)(            \
              gB + (size_t)rb * 1024 + (size_t)(T) * 128),                    \
          (__attribute__((address_space(3))) unsigned int*)(                  \
              Bs + ((T) & 1) * 32768 + rb * 128),                             \
          16, 0, 0);                                                          \
    }                                                                         \
  }

  // ---- fragment reads (swizzled: stored chunk = logical ^ (row&7)) ----
#define READ_A(buf, mh)                                                       \
  {                                                                           \
    _Pragma("unroll") for (int mf = 0; mf < 4; ++mf) {                        \
      const int ro = (wr * 128 + (mh)*64 + mf * 16 + r) * 128;                \
      a[mf][0] = *reinterpret_cast<const short8*>(As + (buf)*32768 + ro + c0);\
      a[mf][1] = *reinterpret_cast<const short8*>(As + (buf)*32768 + ro + c1);\
    }                                                                         \
  }
#define READ_B(buf, nh, BARR)                                                 \
  {                                                                           \
    _Pragma("unroll") for (int nf = 0; nf < 2; ++nf) {                        \
      const int ro = (wc * 64 + (nh)*32 + nf * 16 + r) * 128;                 \
      BARR[nf][0] =                                                           \
          *reinterpret_cast<const short8*>(Bs + (buf)*32768 + ro + c0);       \
      BARR[nf][1] =                                                           \
          *reinterpret_cast<const short8*>(Bs + (buf)*32768 + ro + c1);       \
    }                                                                         \
  }

  // ---- 16-MFMA cluster: 4 m-frags x 2 n-frags x 2 k-steps ----
#define CLUSTER(AO, NO, BARR)                                                 \
  {                                                                           \
    __builtin_amdgcn_s_setprio(1);                                            \
    _Pragma("unroll") for (int k = 0; k < 2; ++k)                             \
    _Pragma("unroll") for (int mf = 0; mf < 4; ++mf)                          \
    _Pragma("unroll") for (int nf = 0; nf < 2; ++nf)                          \
      acc[(AO) + mf][(NO) + nf] = __builtin_amdgcn_mfma_f32_16x16x32_bf16(    \
          a[mf][k], BARR[nf][k], acc[(AO) + mf][(NO) + nf], 0, 0, 0);         \
    __builtin_amdgcn_s_setprio(0);                                            \
  }

  // ---- prologue: 7 half-tiles (tile0 full + tile1 Bnh0,Bnh1,Amh0) ----
  STAGE_B(0, 0);
  STAGE_B(0, 1);
  STAGE_A(0, 0);
  STAGE_A(0, 1);
  STAGE_B(1, 0);
  STAGE_B(1, 1);
  STAGE_A(1, 0);

  // ---- main loop: 4 iterations x 2 K-tiles x 4 quadrant-phases ----
#pragma unroll
  for (int it = 0; it < 4; ++it) {
    const int a0 = 2 * it;
    // ph1: tile a0 (buf0), quadrant (mh0, nh0)
    VMCNT(8);
    BAR();
    READ_A(0, 0);
    READ_B(0, 0, b0);
    STAGE_A(a0 + 1, 1);  // Amh1 of odd tile -> buf1
    CLUSTER(0, 0, b0);
    // ph2: (mh0, nh1) — A cached
    BAR();
    READ_B(0, 1, b1);
    if (it < 3) STAGE_B(a0 + 2, 0);
    CLUSTER(0, 2, b1);
    // ph3: (mh1, nh0) — B0 cached
    if (it < 3) {
      VMCNT(10);
    } else {
      VMCNT(8);
    }
    BAR();
    READ_A(0, 1);
    if (it < 3) STAGE_B(a0 + 2, 1);
    CLUSTER(4, 0, b0);
    // ph4: (mh1, nh1) — all cached
    BAR();
    if (it < 3) STAGE_A(a0 + 2, 0);
    CLUSTER(4, 2, b1);
    // ph5: tile a0+1 (buf1), (mh0, nh0)
    if (it < 3) {
      VMCNT(8);
    } else {
      VMCNT(2);
    }
    BAR();
    READ_A(1, 0);
    READ_B(1, 0, b0);
    if (it < 3) STAGE_A(a0 + 2, 1);
    CLUSTER(0, 0, b0);
    // ph6: (mh0, nh1)
    BAR();
    READ_B(1, 1, b1);
    if (it < 3) STAGE_B(a0 + 3, 0);
    CLUSTER(0, 2, b1);
    // ph7: (mh1, nh0)
    if (it < 3) {
      VMCNT(10);
    } else {
      VMCNT(0);
    }
    BAR();
    READ_A(1, 1);
    if (it < 3) STAGE_B(a0 + 3, 1);
    CLUSTER(4, 0, b0);
    // ph8: (mh1, nh1)
    BAR();
    if (it < 3) STAGE_A(a0 + 3, 0);
    CLUSTER(4, 2, b1);
  }
#undef STAGE_A
#undef STAGE_B
#undef READ_A
#undef READ_B
#undef CLUSTER

  // ---- epilogue: uni = logsig(-s*INV_T); reduce this wave's 64 cols ----
  float part[32];
#pragma unroll
  for (int am = 0; am < 8; ++am)
#pragma unroll
    for (int rr = 0; rr < 4; ++rr) {
      float ssum = 0.0f;
#pragma unroll
      for (int an = 0; an < 4; ++an) {
        float s = acc[am][an][rr] * INV_T;
        ssum += logsig_neg(s);
      }
      part[am * 4 + rr] = ssum;
    }
#pragma unroll
  for (int i = 0; i < 32; ++i) {
    float v = part[i];
    v += __shfl_xor(v, 1);
    v += __shfl_xor(v, 2);
    v += __shfl_xor(v, 4);
    v += __shfl_xor(v, 8);
    part[i] = v;
  }
  if ((lane & 15) == 0) {
    const int gq = lane >> 4;  // row quad within fragment
#pragma unroll
    for (int am = 0; am < 8; ++am)
#pragma unroll
      for (int rr = 0; rr < 4; ++rr)
        atomicAdd(&rowsum[brow + wr * 128 + am * 16 + gq * 4 + rr],
                  part[am * 4 + rr]);
  }
}

__global__ __launch_bounds__(256) void nce_combine(
    const float* __restrict__ ref, const float* __restrict__ pos,
    const float* __restrict__ rowsum, float* __restrict__ out) {
  const int wid  = threadIdx.x >> 6;
  const int lane = threadIdx.x & 63;
  const int n    = blockIdx.x * 4 + wid;

  const f32x4* pr =
      reinterpret_cast<const f32x4*>(ref + (size_t)n * D_ + lane * 8);
  const f32x4* pp =
      reinterpret_cast<const f32x4*>(pos + (size_t)n * D_ + lane * 8);
  f32x4 a0 = pr[0], a1 = pr[1], b0 = pp[0], b1 = pp[1];
  float d = 0.0f;
#pragma unroll
  for (int i = 0; i < 4; ++i) d = __builtin_fmaf(a0[i], b0[i], d);
#pragma unroll
  for (int i = 0; i < 4; ++i) d = __builtin_fmaf(a1[i], b1[i], d);
#pragma unroll
  for (int s = 1; s < 64; s <<= 1) d += __shfl_xor(d, s);

  if (lane == 0) {
    float z = d * INV_T;
    float align   = logsig_neg(-z);
    float uniform = rowsum[n] * (1.0f / (float)M_);
    out[n]          = align + NEG_W * uniform;
    out[N_ + n]     = align;
    out[2 * N_ + n] = uniform;
  }
}

extern "C" void kernel_launch(void* const* d_in, const int* in_sizes, int n_in,
                              void* d_out, int out_size, void* d_ws,
                              size_t ws_size, hipStream_t stream) {
  const float* ref = (const float*)d_in[0];
  const float* pos = (const float*)d_in[1];
  const float* neg = (const float*)d_in[2];
  float* out = (float*)d_out;

  float* rowsum = (float*)d_ws;                                  // 32 KB
  unsigned short* abf = (unsigned short*)((char*)d_ws + 32768);  // 8 MB
  unsigned short* bbf = abf + (size_t)N_ * D_;                   // 8 MB

  (void)hipFuncSetAttribute((const void*)nce_gemm,
                            hipFuncAttributeMaxDynamicSharedMemorySize,
                            131072);

  hipMemsetAsync(rowsum, 0, N_ * sizeof(float), stream);
  cvt_pack<<<4096, 256, 0, stream>>>(ref, neg, abf, bbf);
  nce_gemm<<<1024, 512, 131072, stream>>>(abf, bbf, rowsum);
  nce_combine<<<N_ / 4, 256, 0, stream>>>(ref, pos, rowsum, out);
}